// Round 11
// baseline (4938.604 us; speedup 1.0000x reference)
//
#include <hip/hip_runtime.h>

// Problem constants (fixed by reference setup_inputs)
#define BB 4
#define LL 4096
#define MM 1024
#define DD 2048
#define SEG 128
#define SM 8            // MM / SEG
#define NSCAN (BB * SEG * 2)    // 1024 scan/scatter blocks (2 d-slices of 1024)
#define BCAST 256               // broadcast blocks for the clipped tail

typedef float f32x4 __attribute__((ext_vector_type(4)));

// ---------------------------------------------------------------------------
// Kernel A: per-batch prep.
//  - block-wide cumsum of boundary_mask over L (1024 thr x 4)
//  - scatter clipped p into p_chunked (stable partition: boundary first)
//  - row_start[b][t] = first l with chunk_idx(l)==t  (chunk_idx monotone,
//    steps by +1) ; unreached t stay LL. row_start[b][1024] = LL.
//  - Ppref[b][t] = 8-wide in-segment inclusive prefix product of a[t],
//    a[0]=0, a[t]=1-p[t].
// ---------------------------------------------------------------------------
__global__ __launch_bounds__(1024) void prep_kernel(
    const float* __restrict__ bprob,   // (B, L, 2)
    const int*   __restrict__ bmask,   // (B, L)
    float* __restrict__ p_chunked,     // (B, M)
    int*   __restrict__ row_start,     // (B, 1025)
    float* __restrict__ Ppref)         // (B, M)
{
    const int b   = blockIdx.x;
    const int tid = threadIdx.x;
    const int lane = tid & 63;
    const int wid  = tid >> 6;

    __shared__ int wsum[16];
    __shared__ int s_total;
    __shared__ int rs_sh[MM + 1];

    rs_sh[tid] = LL;
    if (tid == 0) rs_sh[MM] = LL;

    int4 mv = reinterpret_cast<const int4*>(bmask + b * LL)[tid];
    int ms[4] = { mv.x, mv.y, mv.z, mv.w };
    int s = ms[0] + ms[1] + ms[2] + ms[3];

    int v = s;
    #pragma unroll
    for (int off = 1; off < 64; off <<= 1) {
        int u = __shfl_up(v, off, 64);
        if (lane >= off) v += u;
    }
    if (lane == 63) wsum[wid] = v;
    __syncthreads();
    if (tid == 0) {
        int acc = 0;
        #pragma unroll
        for (int w = 0; w < 16; ++w) { int t = wsum[w]; wsum[w] = acc; acc += t; }
        s_total = acc;
    }
    __syncthreads();

    const int NB = s_total;
    int e = (v - s) + wsum[wid];            // exclusive cumsum before elem

    const int base_l = tid * 4;
    #pragma unroll
    for (int j = 0; j < 4; ++j) {
        int l = base_l + j;
        int m = ms[j];
        int incl = e + m;
        int ci = incl - 1;
        ci = ci < 0 ? 0 : (ci > MM - 1 ? MM - 1 : ci);
        int pci = e - 1;
        pci = pci < 0 ? 0 : (pci > MM - 1 ? MM - 1 : pci);
        if (l == 0 || ci != pci) rs_sh[ci] = l;   // unique writer per t
        int pos = m ? e : (NB + (l - e));
        if (pos < MM) {
            float2 pv = *reinterpret_cast<const float2*>(
                bprob + ((size_t)b * LL + l) * 2);
            float p = fminf(fmaxf(pv.y, 1e-4f), 1.0f - 1e-4f);
            p_chunked[b * MM + pos] = p;
        }
        e = incl;
    }
    __syncthreads();

    row_start[b * (MM + 1) + tid] = rs_sh[tid];
    if (tid == 0) row_start[b * (MM + 1) + MM] = rs_sh[MM];

    // 8-wide in-segment prefix products
    {
        int t = tid;
        float p = p_chunked[b * MM + t];
        float a = (t == 0) ? 0.0f : (1.0f - p);
        float pr = a;
        #pragma unroll
        for (int off = 1; off < SM; off <<= 1) {
            float u = __shfl_up(pr, off, SM);
            if ((t & (SM - 1)) >= off) pr *= u;
        }
        Ppref[b * MM + t] = pr;
    }
}

// ---------------------------------------------------------------------------
// Fused kernel: segmented scan (regs) + decoupled lookback + direct scatter.
// Blocks [0, NSCAN): (dsl, seg, b); block owns 8 chunk rows x 1024-float
//   d-slice. Publishes segment-last (agent atomics + flag), full lookback
//   walk (batched 8) for carry, writes corrected rows straight to out over
//   the contiguous l-range of each chunk. Chunk M-1 (clipped tail) skipped.
// Blocks [NSCAN, NSCAN+BCAST): spin on seg-127 inclusive, stream the tail.
// Deadlock-safe: blocks wait only on lower block ids (in-order dispatch).
// ---------------------------------------------------------------------------
__global__ __launch_bounds__(256, 4) void fused_kernel(
    const float* __restrict__ x,          // (B, M, D)
    const float* __restrict__ p_chunked,  // (B, M)
    const float* __restrict__ Ppref,      // (B, M)
    const int*   __restrict__ row_start,  // (B, 1025)
    float* __restrict__ locbuf,           // (B, SEG, D) payload
    float* __restrict__ inclbuf,          // (B, 2, 1024) y[M-1] slices
    int*   __restrict__ flags,            // [0,1024): seg flags; [1024,1032): incl flags
    float* __restrict__ out)              // (B, L, D)
{
    const int id  = blockIdx.x;
    const int tid = threadIdx.x;

    if (id < NSCAN) {
        const int dsl = id & 1;
        const int seg = (id >> 1) & (SEG - 1);
        const int b   = id >> 8;
        const int d0  = dsl * 1024 + tid * 4;
        const int t0  = seg * SM;

        __shared__ float sp[SM], spp[SM], sPseg[SEG];
        if (tid < SM) {
            sp[tid]  = p_chunked[b * MM + t0 + tid];
            spp[tid] = Ppref[b * MM + t0 + tid];
        }
        if (tid < SEG) sPseg[tid] = Ppref[b * MM + tid * SM + SM - 1];
        __syncthreads();

        // ---- local segment scan, rows kept in registers ----
        f32x4 yl[SM];
        f32x4 prev = {0.0f, 0.0f, 0.0f, 0.0f};
        const size_t base = ((size_t)b * MM + t0) * DD + d0;
        #pragma unroll
        for (int i = 0; i < SM; ++i) {
            float p = sp[i];
            float ac, bc;
            if (i == 0) { ac = (seg == 0) ? 0.0f : (1.0f - p); bc = (seg == 0) ? 1.0f : p; }
            else        { ac = 1.0f - p; bc = p; }
            f32x4 xt = *reinterpret_cast<const f32x4*>(x + base + (size_t)i * DD);
            prev = ac * prev + bc * xt;
            yl[i] = prev;
        }

        // ---- publish segment-last (agent-scope) ----
        {
            size_t po = (size_t)(b * SEG + seg) * DD + d0;
            #pragma unroll
            for (int k = 0; k < 4; ++k)
                __hip_atomic_store(&locbuf[po + k], prev[k],
                                   __ATOMIC_RELAXED, __HIP_MEMORY_SCOPE_AGENT);
        }
        __syncthreads();   // drains vmcnt -> payload visible before flag
        if (tid == 0)
            __hip_atomic_store(&flags[(b * SEG + seg) * 2 + dsl], 1,
                               __ATOMIC_RELEASE, __HIP_MEMORY_SCOPE_AGENT);

        // ---- deterministic full lookback walk (batches of 8) ----
        f32x4 carry = {0.0f, 0.0f, 0.0f, 0.0f};
        float mult = 1.0f;
        int s2 = seg - 1;
        while (s2 >= 0) {
            int n = (s2 >= 7) ? 8 : (s2 + 1);
            int fl[8];
            #pragma unroll
            for (int j = 0; j < 8; ++j) if (j < n)
                fl[j] = __hip_atomic_load(&flags[(b * SEG + (s2 - j)) * 2 + dsl],
                                          __ATOMIC_ACQUIRE, __HIP_MEMORY_SCOPE_AGENT);
            #pragma unroll
            for (int j = 0; j < 8; ++j) if (j < n) {
                while (fl[j] == 0)
                    fl[j] = __hip_atomic_load(&flags[(b * SEG + (s2 - j)) * 2 + dsl],
                                              __ATOMIC_ACQUIRE, __HIP_MEMORY_SCOPE_AGENT);
            }
            float pl[8][4];
            #pragma unroll
            for (int j = 0; j < 8; ++j) if (j < n) {
                size_t po = (size_t)(b * SEG + (s2 - j)) * DD + d0;
                #pragma unroll
                for (int k = 0; k < 4; ++k)
                    pl[j][k] = __hip_atomic_load(&locbuf[po + k],
                                                 __ATOMIC_RELAXED, __HIP_MEMORY_SCOPE_AGENT);
            }
            #pragma unroll
            for (int j = 0; j < 8; ++j) if (j < n) {
                int ss = s2 - j;
                carry.x += mult * pl[j][0];
                carry.y += mult * pl[j][1];
                carry.z += mult * pl[j][2];
                carry.w += mult * pl[j][3];
                mult *= sPseg[ss];
            }
            s2 -= n;
        }

        // ---- seg 127 publishes the inclusive y[M-1] for broadcasters ----
        if (seg == SEG - 1) {
            f32x4 incl = yl[SM - 1] + spp[SM - 1] * carry;
            #pragma unroll
            for (int k = 0; k < 4; ++k)
                __hip_atomic_store(&inclbuf[(b * 2 + dsl) * 1024 + tid * 4 + k],
                                   incl[k], __ATOMIC_RELAXED, __HIP_MEMORY_SCOPE_AGENT);
            __syncthreads();
            if (tid == 0)
                __hip_atomic_store(&flags[1024 + b * 2 + dsl], 1,
                                   __ATOMIC_RELEASE, __HIP_MEMORY_SCOPE_AGENT);
        }

        // ---- direct scatter: each chunk row -> its contiguous out range ----
        const int* rs = row_start + b * (MM + 1);
        #pragma unroll
        for (int i = 0; i < SM; ++i) {
            int t = t0 + i;
            if (t == MM - 1) continue;        // tail handled by broadcasters
            f32x4 v = yl[i] + spp[i] * carry;
            int l0r = rs[t], l1r = rs[t + 1];
            for (int l = l0r; l < l1r; ++l)
                *reinterpret_cast<f32x4*>(out + ((size_t)b * LL + l) * DD + d0) = v;
        }
    } else {
        // ---- broadcast blocks: stream y[M-1] over the clipped tail ----
        const int j    = id - NSCAN;          // 0..BCAST-1
        const int g    = j & 7;
        const int chnk = j >> 3;              // 0..31
        const int b    = g >> 1;
        const int dsl  = g & 1;
        const int d0   = dsl * 1024 + tid * 4;

        while (__hip_atomic_load(&flags[1024 + b * 2 + dsl],
                                 __ATOMIC_ACQUIRE, __HIP_MEMORY_SCOPE_AGENT) == 0)
            __builtin_amdgcn_s_sleep(8);

        f32x4 v;
        #pragma unroll
        for (int k = 0; k < 4; ++k)
            v[k] = __hip_atomic_load(&inclbuf[(b * 2 + dsl) * 1024 + tid * 4 + k],
                                     __ATOMIC_RELAXED, __HIP_MEMORY_SCOPE_AGENT);

        const int l0 = row_start[b * (MM + 1) + (MM - 1)];
        for (int l = l0 + chnk; l < LL; l += 32)
            *reinterpret_cast<f32x4*>(out + ((size_t)b * LL + l) * DD + d0) = v;
    }
}

// ---------------------------------------------------------------------------
extern "C" void kernel_launch(void* const* d_in, const int* in_sizes, int n_in,
                              void* d_out, int out_size, void* d_ws, size_t ws_size,
                              hipStream_t stream) {
    const float* x     = (const float*)d_in[0];   // chunked_states (B,M,D) f32
    const float* bprob = (const float*)d_in[1];   // boundary_prob  (B,L,2) f32
    const int*   bmask = (const int*)d_in[2];     // boundary_mask  (B,L) int

    float* out = (float*)d_out;

    // workspace layout (~4.2 MB)
    float* locbuf    = (float*)d_ws;                              // B*SEG*D
    float* inclbuf   = locbuf + (size_t)BB * SEG * DD;            // B*2*1024
    float* p_chunked = inclbuf + BB * 2 * 1024;                   // B*M
    float* Ppref     = p_chunked + BB * MM;                       // B*M
    int*   row_start = (int*)(Ppref + BB * MM);                   // B*1025
    int*   flags     = row_start + BB * (MM + 1);                 // 1024 + 8 ints

    hipMemsetAsync(flags, 0, (NSCAN + 8) * sizeof(int), stream);
    prep_kernel<<<BB, 1024, 0, stream>>>(bprob, bmask, p_chunked, row_start, Ppref);
    fused_kernel<<<NSCAN + BCAST, 256, 0, stream>>>(
        x, p_chunked, Ppref, row_start, locbuf, inclbuf, flags, out);
}

// Round 12
// 52.788 us; speedup vs baseline: 93.5546x; 93.5546x over previous
//
#include <hip/hip_runtime.h>

// Problem constants (fixed by reference setup_inputs)
#define BB 4
#define LL 4096
#define MM 1024
#define DD 2048
#define SEG 128
#define SM 8            // MM / SEG
#define NSCAN (BB * SEG * 2)    // 1024 scan/scatter blocks (2 d-slices of 1024)
#define BCAST 1024              // tail broadcast blocks

typedef float f32x4 __attribute__((ext_vector_type(4)));

// ---------------------------------------------------------------------------
// Kernel A: per-batch prep (proven in R11).
//  - block-wide cumsum of boundary_mask over L
//  - scatter clipped p into p_chunked (stable partition)
//  - row_start[b][t] = first l with chunk_idx(l)==t (monotone); LL if none.
//  - Ppref[b][t] = 8-wide in-segment inclusive prefix product of a[t]
// ---------------------------------------------------------------------------
__global__ __launch_bounds__(1024) void prep_kernel(
    const float* __restrict__ bprob,   // (B, L, 2)
    const int*   __restrict__ bmask,   // (B, L)
    float* __restrict__ p_chunked,     // (B, M)
    int*   __restrict__ row_start,     // (B, 1025)
    float* __restrict__ Ppref)         // (B, M)
{
    const int b   = blockIdx.x;
    const int tid = threadIdx.x;
    const int lane = tid & 63;
    const int wid  = tid >> 6;

    __shared__ int wsum[16];
    __shared__ int s_total;
    __shared__ int rs_sh[MM + 1];

    rs_sh[tid] = LL;
    if (tid == 0) rs_sh[MM] = LL;

    int4 mv = reinterpret_cast<const int4*>(bmask + b * LL)[tid];
    int ms[4] = { mv.x, mv.y, mv.z, mv.w };
    int s = ms[0] + ms[1] + ms[2] + ms[3];

    int v = s;
    #pragma unroll
    for (int off = 1; off < 64; off <<= 1) {
        int u = __shfl_up(v, off, 64);
        if (lane >= off) v += u;
    }
    if (lane == 63) wsum[wid] = v;
    __syncthreads();
    if (tid == 0) {
        int acc = 0;
        #pragma unroll
        for (int w = 0; w < 16; ++w) { int t = wsum[w]; wsum[w] = acc; acc += t; }
        s_total = acc;
    }
    __syncthreads();

    const int NB = s_total;
    int e = (v - s) + wsum[wid];            // exclusive cumsum before elem

    const int base_l = tid * 4;
    #pragma unroll
    for (int j = 0; j < 4; ++j) {
        int l = base_l + j;
        int m = ms[j];
        int incl = e + m;
        int ci = incl - 1;
        ci = ci < 0 ? 0 : (ci > MM - 1 ? MM - 1 : ci);
        int pci = e - 1;
        pci = pci < 0 ? 0 : (pci > MM - 1 ? MM - 1 : pci);
        if (l == 0 || ci != pci) rs_sh[ci] = l;   // unique writer per t
        int pos = m ? e : (NB + (l - e));
        if (pos < MM) {
            float2 pv = *reinterpret_cast<const float2*>(
                bprob + ((size_t)b * LL + l) * 2);
            float p = fminf(fmaxf(pv.y, 1e-4f), 1.0f - 1e-4f);
            p_chunked[b * MM + pos] = p;
        }
        e = incl;
    }
    __syncthreads();

    row_start[b * (MM + 1) + tid] = rs_sh[tid];
    if (tid == 0) row_start[b * (MM + 1) + MM] = rs_sh[MM];

    // 8-wide in-segment prefix products
    {
        int t = tid;
        float p = p_chunked[b * MM + t];
        float a = (t == 0) ? 0.0f : (1.0f - p);
        float pr = a;
        #pragma unroll
        for (int off = 1; off < SM; off <<= 1) {
            float u = __shfl_up(pr, off, SM);
            if ((t & (SM - 1)) >= off) pr *= u;
        }
        Ppref[b * MM + t] = pr;
    }
}

// ---------------------------------------------------------------------------
// Kernel B: per-segment scan emitting ONLY the segment-end value.
// grid = (2, 128, 4) = 1024 blocks, block = 256, f32x4 per thread.
// ---------------------------------------------------------------------------
__global__ __launch_bounds__(256) void seglast_kernel(
    const float* __restrict__ x,          // (B, M, D)
    const float* __restrict__ p_chunked,  // (B, M)
    float* __restrict__ seglast)          // (B, SEG, D)
{
    const int tid = threadIdx.x;
    const int d0  = blockIdx.x * 1024 + tid * 4;
    const int seg = blockIdx.y;
    const int b   = blockIdx.z;
    const int t0  = seg * SM;

    __shared__ float sp[SM];
    if (tid < SM) sp[tid] = p_chunked[b * MM + t0 + tid];
    __syncthreads();

    const size_t base = ((size_t)b * MM + t0) * DD + d0;

    f32x4 prev = {0.0f, 0.0f, 0.0f, 0.0f};
    #pragma unroll
    for (int i = 0; i < SM; ++i) {
        float p = sp[i];
        float ac, bc;
        if (i == 0) { ac = (seg == 0) ? 0.0f : (1.0f - p); bc = (seg == 0) ? 1.0f : p; }
        else        { ac = 1.0f - p; bc = p; }
        f32x4 xt = *reinterpret_cast<const f32x4*>(x + base + (size_t)i * DD);
        prev = ac * prev + bc * xt;
    }
    *reinterpret_cast<f32x4*>(seglast + ((size_t)b * SEG + seg) * DD + d0) = prev;
}

// ---------------------------------------------------------------------------
// Kernel C: carry recurrence IN-PLACE on seglast (-> carry-in per segment),
// and emit yM1[b,d] = full inclusive y[M-1] for the tail broadcast.
// grid = 16 blocks x 256 (B*D/2 float2 threads).
// ---------------------------------------------------------------------------
__global__ __launch_bounds__(256) void carry_kernel(
    float* __restrict__ buf,              // (B, SEG, D): seglast -> carry
    const float* __restrict__ Ppref,      // (B, M)
    float* __restrict__ yM1)              // (B, D)
{
    int idx = blockIdx.x * 256 + threadIdx.x;   // over B*D/2
    int b  = idx / (DD / 2);
    int d2 = (idx % (DD / 2)) * 2;

    float2 run = make_float2(0.0f, 0.0f);
    #pragma unroll 8
    for (int s = 0; s < SEG; ++s) {
        float* addr = buf + ((size_t)b * SEG + s) * DD + d2;
        float2 last = *reinterpret_cast<const float2*>(addr);   // read first
        *reinterpret_cast<float2*>(addr) = run;                 // then write
        float Pf = Ppref[b * MM + s * SM + SM - 1];             // uniform
        run.x = fmaf(Pf, run.x, last.x);
        run.y = fmaf(Pf, run.y, last.y);
    }
    *reinterpret_cast<float2*>(yM1 + (size_t)b * DD + d2) = run;
}

// ---------------------------------------------------------------------------
// Kernel D: direct scatter.
// Scan blocks [0,NSCAN): (b,seg,dsl) re-scan x (LLC-hot) seeded with the
//   precomputed carry-in, write each chunk's value to its contiguous
//   out-row range [row_start[t], row_start[t+1]). Chunk M-1 skipped.
// Broadcast blocks [NSCAN, NSCAN+BCAST): stream yM1 over the clipped tail.
// No inter-block waits anywhere.
// ---------------------------------------------------------------------------
__global__ __launch_bounds__(256) void scatter_kernel(
    const float* __restrict__ x,          // (B, M, D)
    const float* __restrict__ p_chunked,  // (B, M)
    const int*   __restrict__ row_start,  // (B, 1025)
    const float* __restrict__ carry,      // (B, SEG, D) carry-in per segment
    const float* __restrict__ yM1,        // (B, D)
    float* __restrict__ out)              // (B, L, D)
{
    const int id  = blockIdx.x;
    const int tid = threadIdx.x;

    if (id < NSCAN) {
        const int dsl = id & 1;
        const int seg = (id >> 1) & (SEG - 1);
        const int b   = id >> 8;
        const int d0  = dsl * 1024 + tid * 4;
        const int t0  = seg * SM;

        __shared__ float sp[SM];
        __shared__ int   rs[SM + 1];
        if (tid < SM) sp[tid] = p_chunked[b * MM + t0 + tid];
        if (tid < SM + 1) rs[tid] = row_start[b * (MM + 1) + t0 + tid];
        __syncthreads();

        // seed with carry-in, then run the true recurrence
        f32x4 prev = *reinterpret_cast<const f32x4*>(
            carry + ((size_t)(b * SEG + seg)) * DD + d0);
        const size_t base = ((size_t)b * MM + t0) * DD + d0;

        #pragma unroll
        for (int i = 0; i < SM; ++i) {
            float p = sp[i];
            float ac, bc;
            if (i == 0) { ac = (seg == 0) ? 0.0f : (1.0f - p); bc = (seg == 0) ? 1.0f : p; }
            else        { ac = 1.0f - p; bc = p; }
            f32x4 xt = *reinterpret_cast<const f32x4*>(x + base + (size_t)i * DD);
            prev = ac * prev + bc * xt;

            int t = t0 + i;
            if (t == MM - 1) continue;        // tail handled by broadcasters
            int l0r = rs[i], l1r = rs[i + 1];
            for (int l = l0r; l < l1r; ++l)
                *reinterpret_cast<f32x4*>(out + ((size_t)b * LL + l) * DD + d0) = prev;
        }
    } else {
        // tail broadcast: out rows [row_start[M-1], LL) all equal yM1
        const int j    = id - NSCAN;          // 0..BCAST-1
        const int g    = j & 7;               // (b, dsl)
        const int chnk = j >> 3;              // 0..127
        const int b    = g >> 1;
        const int dsl  = g & 1;
        const int d0   = dsl * 1024 + tid * 4;

        f32x4 v = *reinterpret_cast<const f32x4*>(yM1 + (size_t)b * DD + d0);
        const int l0 = row_start[b * (MM + 1) + (MM - 1)];
        for (int l = l0 + chnk; l < LL; l += 128)
            *reinterpret_cast<f32x4*>(out + ((size_t)b * LL + l) * DD + d0) = v;
    }
}

// ---------------------------------------------------------------------------
extern "C" void kernel_launch(void* const* d_in, const int* in_sizes, int n_in,
                              void* d_out, int out_size, void* d_ws, size_t ws_size,
                              hipStream_t stream) {
    const float* x     = (const float*)d_in[0];   // chunked_states (B,M,D) f32
    const float* bprob = (const float*)d_in[1];   // boundary_prob  (B,L,2) f32
    const int*   bmask = (const int*)d_in[2];     // boundary_mask  (B,L) int

    float* out = (float*)d_out;

    // workspace layout (~4.2 MB)
    float* buf       = (float*)d_ws;                          // B*SEG*D (seglast->carry)
    float* yM1       = buf + (size_t)BB * SEG * DD;           // B*D
    float* p_chunked = yM1 + BB * DD;                         // B*M
    float* Ppref     = p_chunked + BB * MM;                   // B*M
    int*   row_start = (int*)(Ppref + BB * MM);               // B*1025

    prep_kernel<<<BB, 1024, 0, stream>>>(bprob, bmask, p_chunked, row_start, Ppref);
    seglast_kernel<<<dim3(DD / 1024, SEG, BB), 256, 0, stream>>>(x, p_chunked, buf);
    carry_kernel<<<(BB * DD / 2) / 256, 256, 0, stream>>>(buf, Ppref, yM1);
    scatter_kernel<<<NSCAN + BCAST, 256, 0, stream>>>(
        x, p_chunked, row_start, buf, yM1, out);
}